// Round 1
// baseline (1728.097 us; speedup 1.0000x reference)
//
#include <hip/hip_runtime.h>
#include <cstdint>

#define N_TOTAL 10000
#define D 128
#define FEAT 3072
#define BS_BN 100
#define TOPK 50

typedef unsigned int uint;
typedef unsigned long long ull;
typedef unsigned short u16;
typedef short short8 __attribute__((ext_vector_type(8)));
typedef float f32x4 __attribute__((ext_vector_type(4)));
union U16 { uint4 u; short8 b; };

// Split fp32 -> bf16 hi (truncate) + bf16 lo (truncate of residual), 8 at a time.
__device__ inline void split8(float4 f0, float4 f1, U16& h, U16& l) {
  float f[8] = {f0.x, f0.y, f0.z, f0.w, f1.x, f1.y, f1.z, f1.w};
  uint hb[8], lb[8];
#pragma unroll
  for (int e = 0; e < 8; ++e) {
    uint b = __float_as_uint(f[e]);
    uint hx = b & 0xFFFF0000u;
    float lf = f[e] - __uint_as_float(hx);
    hb[e] = b >> 16;
    lb[e] = __float_as_uint(lf) >> 16;
  }
  h.u = make_uint4(hb[0] | (hb[1] << 16), hb[2] | (hb[3] << 16),
                   hb[4] | (hb[5] << 16), hb[6] | (hb[7] << 16));
  l.u = make_uint4(lb[0] | (lb[1] << 16), lb[2] | (lb[3] << 16),
                   lb[4] | (lb[5] << 16), lb[6] | (lb[7] << 16));
}

// ---------------- K1: x = in @ W1^T via split-bf16 MFMA (unchanged, proven) ----------------
__global__ __launch_bounds__(256) void k_gemm1(const float* __restrict__ in,
                                               const float* __restrict__ W1,
                                               float* __restrict__ x) {
  __shared__ alignas(16) float Af[128 * 44];
  __shared__ alignas(16) float Bf[128 * 44];
  const int t = threadIdx.x;
  const int lane = t & 63, wid = t >> 6;
  const int q = lane >> 4, l15 = lane & 15;
  const int i0 = blockIdx.x * 128;
  const int k0 = blockIdx.y * 768;
  const int wm = (wid & 1) * 64, wn = (wid >> 1) * 64;

  f32x4 acc[4][4];
#pragma unroll
  for (int mt = 0; mt < 4; ++mt)
#pragma unroll
    for (int nt = 0; nt < 4; ++nt) acc[mt][nt] = (f32x4){0.f, 0.f, 0.f, 0.f};

  for (int kb = k0; kb < k0 + 768; kb += 32) {
    __syncthreads();
#pragma unroll
    for (int s = 0; s < 4; ++s) {
      int idx = t + 256 * s;
      int row = idx >> 3, f4 = (idx & 7) * 4;
      int gi = i0 + row; if (gi > N_TOTAL - 1) gi = N_TOTAL - 1;
      *(float4*)&Af[row * 44 + f4] = *(const float4*)&in[(size_t)gi * FEAT + kb + f4];
      *(float4*)&Bf[row * 44 + f4] = *(const float4*)&W1[(size_t)row * FEAT + kb + f4];
    }
    __syncthreads();
    U16 Ah[4], Al[4], Bh[4], Bl[4];
#pragma unroll
    for (int mt = 0; mt < 4; ++mt) {
      int ro = (wm + mt * 16 + l15) * 44 + q * 8;
      float4 x0 = *(const float4*)&Af[ro];
      float4 x1 = *(const float4*)&Af[ro + 4];
      split8(x0, x1, Ah[mt], Al[mt]);
    }
#pragma unroll
    for (int nt = 0; nt < 4; ++nt) {
      int ro = (wn + nt * 16 + l15) * 44 + q * 8;
      float4 x0 = *(const float4*)&Bf[ro];
      float4 x1 = *(const float4*)&Bf[ro + 4];
      split8(x0, x1, Bh[nt], Bl[nt]);
    }
#pragma unroll
    for (int mt = 0; mt < 4; ++mt)
#pragma unroll
      for (int nt = 0; nt < 4; ++nt) {
        acc[mt][nt] = __builtin_amdgcn_mfma_f32_16x16x32_bf16(Ah[mt].b, Bh[nt].b, acc[mt][nt], 0, 0, 0);
        acc[mt][nt] = __builtin_amdgcn_mfma_f32_16x16x32_bf16(Ah[mt].b, Bl[nt].b, acc[mt][nt], 0, 0, 0);
        acc[mt][nt] = __builtin_amdgcn_mfma_f32_16x16x32_bf16(Al[mt].b, Bh[nt].b, acc[mt][nt], 0, 0, 0);
      }
  }

#pragma unroll
  for (int mt = 0; mt < 4; ++mt) {
#pragma unroll
    for (int r = 0; r < 4; ++r) {
      int gi = i0 + wm + mt * 16 + q * 4 + r;
      if (gi >= N_TOTAL) continue;
#pragma unroll
      for (int nt = 0; nt < 4; ++nt)
        atomicAdd(&x[(size_t)gi * D + wn + nt * 16 + l15], acc[mt][nt][r]);
    }
  }
}

// ---------------- K2: BatchNorm + pre-split bf16 planes ----------------
// Writes: out_final (fp32 output), outf (fp32, for k_arow), Ah/Al = split(out) linear,
// Bh/Bl = split(out*sw) stored with col ^ ((row&7)<<3) swizzle (bank-conflict-free
// ds_read_b128 in k_fused from a linearly-staged LDS tile).
__global__ __launch_bounds__(128) void k_bn(const float* __restrict__ x,
                                            const float* __restrict__ b1,
                                            const float* __restrict__ gamma,
                                            const float* __restrict__ beta,
                                            const float* __restrict__ sw,
                                            float* __restrict__ out_final,
                                            float* __restrict__ outf,
                                            u16* __restrict__ Ah, u16* __restrict__ Al,
                                            u16* __restrict__ Bh, u16* __restrict__ Bl) {
  const int b = blockIdx.x, c = threadIdx.x;
  const float bias = b1[c];
  float s = 0.f, s2 = 0.f;
  const float* xp = x + (size_t)b * BS_BN * D + c;
  for (int r = 0; r < BS_BN; ++r) {
    float v = xp[(size_t)r * D] + bias;
    s += v; s2 = fmaf(v, v, s2);
  }
  float mean = s * (1.f / BS_BN);
  float var = s2 * (1.f / BS_BN) - mean * mean;
  float scale = gamma[c] * rsqrtf(var + 1e-5f);
  float shift = beta[c] - mean * scale;
  float swc = sw[c];
  float* op  = out_final + (size_t)b * BS_BN * D + c;
  float* ofp = outf + (size_t)b * BS_BN * D + c;
  for (int r = 0; r < BS_BN; ++r) {
    float v = fmaf(xp[(size_t)r * D] + bias, scale, shift);
    op[(size_t)r * D] = v;
    ofp[(size_t)r * D] = v;
    int j = b * BS_BN + r;
    size_t rowo = (size_t)j * D;
    int cs = c ^ ((j & 7) << 3);
    // split(v): identical math to split8
    uint vb = __float_as_uint(v);
    float vl = v - __uint_as_float(vb & 0xFFFF0000u);
    Ah[rowo + c] = (u16)(vb >> 16);
    Al[rowo + c] = (u16)(__float_as_uint(vl) >> 16);
    float w = v * swc;
    uint wb = __float_as_uint(w);
    float wl = w - __uint_as_float(wb & 0xFFFF0000u);
    Bh[rowo + cs] = (u16)(wb >> 16);
    Bl[rowo + cs] = (u16)(__float_as_uint(wl) >> 16);
  }
}

// ---------------- K2b: a[i] = sum_k sw[k]*out[i,k]^2 (unchanged, proven) ----------------
__global__ __launch_bounds__(256) void k_arow(const float* __restrict__ outf,
                                              const float* __restrict__ sw,
                                              float* __restrict__ aarr) {
  const int t = threadIdx.x;
  const int lane = t & 63;
  const int row = blockIdx.x * 4 + (t >> 6);
  float o1 = outf[(size_t)row * D + lane];
  float o2 = outf[(size_t)row * D + 64 + lane];
  float v = sw[lane] * o1 * o1 + sw[64 + lane] * o2 * o2;
#pragma unroll
  for (int off = 32; off >= 1; off >>= 1) v += __shfl_xor(v, off);
  if (lane == 0) aarr[row] = v;
}

// ---------------- K3: fused score + exact streaming top-50 ----------------
// Block = 32 output rows, 1024 threads (16 waves: ifr = wid>>3 in {0,1}, jfr = wid&7).
// A (K=128 hi/lo bf16) lives in registers. Streams 79 j-tiles of 128 columns:
// reg-prefetch tile t+1 from global, ds_write tile t, MFMA (bit-identical to old
// k_score: AhBh, AhBl, AlBh), then threshold-filter candidates into a per-row LDS
// reservoir of 64-bit keys (score_bits<<32 | ~j): descending key order == (value
// desc, index asc) — exactly jax top_k stable-tie semantics incl. ties at zero.
// Reservoir compacted to exact top-50 via wave bitonic-256 when it exceeds FTRIG.
#define FCAP 248
#define FTRIG 120
#define JT 128
#define NT 79

__device__ inline void sort256_desc(ull v[4], int lane) {
#pragma unroll
  for (uint k = 2; k <= 256; k <<= 1) {
    for (uint jj = k >> 1; jj; jj >>= 1) {
      if (jj >= 64) {
        int sj = (int)(jj >> 6);
#pragma unroll
        for (int s = 0; s < 4; ++s) {
          if (!(s & sj)) {
            int sp = s | sj;
            bool up = (((uint)(s * 64) & k) == 0u);
            ull a = v[s], b = v[sp];
            ull mx = a > b ? a : b, mn = a > b ? b : a;
            v[s] = up ? mx : mn;
            v[sp] = up ? mn : mx;
          }
        }
      } else {
#pragma unroll
        for (int s = 0; s < 4; ++s) {
          uint g = (uint)(s * 64 + lane);
          ull o = __shfl_xor(v[s], (int)jj, 64);
          bool up = ((g & k) == 0u);
          bool lower = (((uint)lane & jj) == 0u);
          ull mx = v[s] > o ? v[s] : o;
          ull mn = v[s] > o ? o : v[s];
          v[s] = (up == lower) ? mx : mn;
        }
      }
    }
  }
}

__global__ __launch_bounds__(1024) void k_fused(const u16* __restrict__ Ah,
                                                const u16* __restrict__ Al,
                                                const u16* __restrict__ Bh,
                                                const u16* __restrict__ Bl,
                                                const float* __restrict__ aarr,
                                                const float* __restrict__ sbp,
                                                ull* __restrict__ lists) {
  __shared__ ull resK[32][FCAP];            // 63.5 KB reservoir
  __shared__ ull thrK[32];
  __shared__ uint cntK[32];
  __shared__ alignas(16) u16 Bls[2 * JT * D];  // 64 KB: [plane][row][col(swz)]

  const int t = threadIdx.x;
  const int lane = t & 63, wid = t >> 6;
  const int q = lane >> 4, l15 = lane & 15;
  const int ifr = wid >> 3, jfr = wid & 7;
  const int i0 = blockIdx.x * 32;
  const float sb = sbp[0];

  if (t < 32) { cntK[t] = 0u; thrK[t] = 0ULL; }

  // A fragments (hi/lo) -> registers, 16B loads from linear planes
  int arow = i0 + ifr * 16 + l15; if (arow > N_TOTAL - 1) arow = N_TOTAL - 1;
  uint4 AhR[4], AlR[4];
#pragma unroll
  for (int kk = 0; kk < 4; ++kk) {
    AhR[kk] = *(const uint4*)(Ah + (size_t)arow * D + kk * 32 + q * 8);
    AlR[kk] = *(const uint4*)(Al + (size_t)arow * D + kk * 32 + q * 8);
  }
  float ai[4];
#pragma unroll
  for (int r = 0; r < 4; ++r) {
    int ig = i0 + ifr * 16 + q * 4 + r; if (ig > N_TOTAL - 1) ig = N_TOTAL - 1;
    ai[r] = aarr[ig] + sb;
  }

  const int jl = jfr * 16 + l15;          // 0..127
  const int swz = (jl & 7) << 4;          // byte-XOR for swizzled B reads

  // prefetch tile 0 into regs
  uint4 stg[4];
#pragma unroll
  for (int s = 0; s < 4; ++s) {
    int idx = s * 1024 + t;
    int p = idx >> 11;
    int off = (idx & 2047) * 16;
    int jg = (off >> 8); if (jg > N_TOTAL - 1) jg = N_TOTAL - 1;
    stg[s] = *(const uint4*)((const char*)(p ? Bl : Bh) + (size_t)jg * 256 + (off & 255));
  }

  for (int tile = 0; tile < NT; ++tile) {
    // compaction check on state after previous tile (skip tile 0: cnts uninit-visible)
    if (tile > 0) {
#pragma unroll
      for (int rr = 0; rr < 2; ++rr) {
        int rI = wid + rr * 16;
        uint c = cntK[rI];
        if (c > FTRIG) {
          int cc = (c > (uint)FCAP) ? FCAP : (int)c;
          ull v[4];
#pragma unroll
          for (int s = 0; s < 4; ++s) {
            int g = s * 64 + lane;
            v[s] = (g < cc) ? resK[rI][g] : 0ULL;
          }
          sort256_desc(v, lane);
          if (lane < TOPK) resK[rI][lane] = v[0];
          if (lane == TOPK - 1) thrK[rI] = v[0];
          if (lane == 0) cntK[rI] = TOPK;
        }
      }
    }
    // stage tile's data (prefetched last iter) into LDS
#pragma unroll
    for (int s = 0; s < 4; ++s) {
      int idx = s * 1024 + t;
      int off = (idx & 2047) * 16;
      *(uint4*)((char*)Bls + (idx >> 11) * 32768 + off) = stg[s];
    }
    __syncthreads();  // B1: staged B + compaction thr updates visible

    // prefetch next tile (latency hidden under compute)
    if (tile + 1 < NT) {
      int jb2 = (tile + 1) * JT;
#pragma unroll
      for (int s = 0; s < 4; ++s) {
        int idx = s * 1024 + t;
        int p = idx >> 11;
        int off = (idx & 2047) * 16;
        int jg = jb2 + (off >> 8); if (jg > N_TOTAL - 1) jg = N_TOTAL - 1;
        stg[s] = *(const uint4*)((const char*)(p ? Bl : Bh) + (size_t)jg * 256 + (off & 255));
      }
    }

    const int jb = tile * JT;
    const int jc = jb + jl;
    float ajv = aarr[jc < N_TOTAL ? jc : N_TOTAL - 1];

    // MFMA: same operand order as proven k_score (AhBh, AhBl, AlBh per k-step)
    f32x4 acc = (f32x4){0.f, 0.f, 0.f, 0.f};
    const char* bbase = (const char*)Bls + (size_t)jl * 256;
#pragma unroll
    for (int kk = 0; kk < 4; ++kk) {
      int bo = ((kk * 32 + q * 8) * 2) ^ swz;
      U16 bh, bl, ah, al;
      bh.u = *(const uint4*)(bbase + bo);
      bl.u = *(const uint4*)(bbase + 32768 + bo);
      ah.u = AhR[kk]; al.u = AlR[kk];
      acc = __builtin_amdgcn_mfma_f32_16x16x32_bf16(ah.b, bh.b, acc, 0, 0, 0);
      acc = __builtin_amdgcn_mfma_f32_16x16x32_bf16(ah.b, bl.b, acc, 0, 0, 0);
      acc = __builtin_amdgcn_mfma_f32_16x16x32_bf16(al.b, bh.b, acc, 0, 0, 0);
    }

    // filter into reservoir
    if (jc < N_TOTAL) {
#pragma unroll
      for (int r = 0; r < 4; ++r) {
        int il = ifr * 16 + q * 4 + r;
        float sc = ai[r] + ajv - 2.f * acc[r];
        sc = (sc > 0.f) ? sc : 0.f;
        ull key = ((ull)__float_as_uint(sc) << 32) | (ull)(0xFFFFFFFFu - (uint)jc);
        if (key > thrK[il]) {
          uint pos = atomicAdd(&cntK[il], 1u);
          if (pos < (uint)FCAP) resK[il][pos] = key;
        }
      }
    }
    __syncthreads();  // B2: inserts visible to next compaction check
  }

  // final exact top-50 per row -> lists
#pragma unroll
  for (int rr = 0; rr < 2; ++rr) {
    int rI = wid + rr * 16;
    int ig = i0 + rI;
    uint c = cntK[rI];
    int cc = (c > (uint)FCAP) ? FCAP : (int)c;
    ull v[4];
#pragma unroll
    for (int s = 0; s < 4; ++s) {
      int g = s * 64 + lane;
      v[s] = (g < cc) ? resK[rI][g] : 0ULL;
    }
    sort256_desc(v, lane);
    if (ig < N_TOTAL && lane < TOPK) lists[(size_t)ig * TOPK + lane] = v[0];
  }
}

// ---------------- K4: softmax + sparse write of S (single HBM pass over S) ----------------
__global__ __launch_bounds__(256) void k_write(const ull* __restrict__ lists,
                                               float* __restrict__ S) {
  const int t = threadIdx.x;
  const int lane = t & 63, wid = t >> 6;
  const int row = blockIdx.x * 4 + wid;

  ull key = (lane < TOPK) ? lists[(size_t)row * TOPK + lane] : 0ULL;
  float xv = (lane < TOPK) ? __uint_as_float((uint)(key >> 32)) : -1e30f;
  float mx = xv;
#pragma unroll
  for (int off = 32; off >= 1; off >>= 1) mx = fmaxf(mx, __shfl_xor(mx, off));
  float e = (lane < TOPK) ? expf(xv - mx) : 0.f;
  float ss = e;
#pragma unroll
  for (int off = 32; off >= 1; off >>= 1) ss += __shfl_xor(ss, off);
  float sv = e / ss;
  uint j = 0xFFFFFFFFu - (uint)(key & 0xFFFFFFFFu);

  float4* wp = (float4*)(S + (size_t)row * N_TOTAL);
  float4 z = make_float4(0.f, 0.f, 0.f, 0.f);
  for (int c = lane; c < N_TOTAL / 4; c += 64) wp[c] = z;
  __syncthreads();  // drain zero-stores before scatter (same-address ordering)
  if (lane < TOPK) S[(size_t)row * N_TOTAL + j] = sv;
}

extern "C" void kernel_launch(void* const* d_in, const int* in_sizes, int n_in,
                              void* d_out, int out_size, void* d_ws, size_t ws_size,
                              hipStream_t stream) {
  const float* in    = (const float*)d_in[0];
  const float* W1    = (const float*)d_in[1];
  const float* b1    = (const float*)d_in[2];
  const float* gamma = (const float*)d_in[3];
  const float* beta  = (const float*)d_in[4];
  const float* sw    = (const float*)d_in[5];
  const float* sb    = (const float*)d_in[6];
  float* out_f = (float*)d_out;
  float* S = out_f + (size_t)N_TOTAL * D;  // [10000,10000]

  // ws layout (~24.6 MB)
  float* wsf  = (float*)d_ws;
  float* x    = wsf;                               // 1,280,000 f
  float* outf = wsf + 1280000;                     // 1,280,000 f
  float* aarr = wsf + 2560000;                     // 10,000 f
  u16* Ah = (u16*)(wsf + 2570000);                 // 1,280,000 u16 each
  u16* Al = Ah + 1280000;
  u16* Bh = Al + 1280000;
  u16* Bl = Bh + 1280000;
  ull* lists = (ull*)(Bl + 1280000);               // 10000*50 u64 = 4 MB

  hipMemsetAsync(x, 0, (size_t)N_TOTAL * D * sizeof(float), stream);
  k_gemm1<<<dim3(79, 4), 256, 0, stream>>>(in, W1, x);
  k_bn<<<100, 128, 0, stream>>>(x, b1, gamma, beta, sw, out_f, outf, Ah, Al, Bh, Bl);
  k_arow<<<2500, 256, 0, stream>>>(outf, sw, aarr);
  k_fused<<<313, 1024, 0, stream>>>(Ah, Al, Bh, Bl, aarr, sb, lists);
  k_write<<<2500, 256, 0, stream>>>(lists, S);
}

// Round 2
// 1725.211 us; speedup vs baseline: 1.0017x; 1.0017x over previous
//
#include <hip/hip_runtime.h>
#include <cstdint>

#define N_TOTAL 10000
#define D 128
#define FEAT 3072
#define BS_BN 100
#define TOPK 50

typedef unsigned int uint;
typedef unsigned long long ull;
typedef unsigned short u16;
typedef short short8 __attribute__((ext_vector_type(8)));
typedef float f32x4 __attribute__((ext_vector_type(4)));
union U16 { uint4 u; short8 b; };

// Split fp32 -> bf16 hi (truncate) + bf16 lo (truncate of residual), 8 at a time.
__device__ inline void split8(float4 f0, float4 f1, U16& h, U16& l) {
  float f[8] = {f0.x, f0.y, f0.z, f0.w, f1.x, f1.y, f1.z, f1.w};
  uint hb[8], lb[8];
#pragma unroll
  for (int e = 0; e < 8; ++e) {
    uint b = __float_as_uint(f[e]);
    uint hx = b & 0xFFFF0000u;
    float lf = f[e] - __uint_as_float(hx);
    hb[e] = b >> 16;
    lb[e] = __float_as_uint(lf) >> 16;
  }
  h.u = make_uint4(hb[0] | (hb[1] << 16), hb[2] | (hb[3] << 16),
                   hb[4] | (hb[5] << 16), hb[6] | (hb[7] << 16));
  l.u = make_uint4(lb[0] | (lb[1] << 16), lb[2] | (lb[3] << 16),
                   lb[4] | (lb[5] << 16), lb[6] | (lb[7] << 16));
}

// ---------------- K1: x = in @ W1^T via split-bf16 MFMA (unchanged, proven) ----------------
__global__ __launch_bounds__(256) void k_gemm1(const float* __restrict__ in,
                                               const float* __restrict__ W1,
                                               float* __restrict__ x) {
  __shared__ alignas(16) float Af[128 * 44];
  __shared__ alignas(16) float Bf[128 * 44];
  const int t = threadIdx.x;
  const int lane = t & 63, wid = t >> 6;
  const int q = lane >> 4, l15 = lane & 15;
  const int i0 = blockIdx.x * 128;
  const int k0 = blockIdx.y * 768;
  const int wm = (wid & 1) * 64, wn = (wid >> 1) * 64;

  f32x4 acc[4][4];
#pragma unroll
  for (int mt = 0; mt < 4; ++mt)
#pragma unroll
    for (int nt = 0; nt < 4; ++nt) acc[mt][nt] = (f32x4){0.f, 0.f, 0.f, 0.f};

  for (int kb = k0; kb < k0 + 768; kb += 32) {
    __syncthreads();
#pragma unroll
    for (int s = 0; s < 4; ++s) {
      int idx = t + 256 * s;
      int row = idx >> 3, f4 = (idx & 7) * 4;
      int gi = i0 + row; if (gi > N_TOTAL - 1) gi = N_TOTAL - 1;
      *(float4*)&Af[row * 44 + f4] = *(const float4*)&in[(size_t)gi * FEAT + kb + f4];
      *(float4*)&Bf[row * 44 + f4] = *(const float4*)&W1[(size_t)row * FEAT + kb + f4];
    }
    __syncthreads();
    U16 Ah[4], Al[4], Bh[4], Bl[4];
#pragma unroll
    for (int mt = 0; mt < 4; ++mt) {
      int ro = (wm + mt * 16 + l15) * 44 + q * 8;
      float4 x0 = *(const float4*)&Af[ro];
      float4 x1 = *(const float4*)&Af[ro + 4];
      split8(x0, x1, Ah[mt], Al[mt]);
    }
#pragma unroll
    for (int nt = 0; nt < 4; ++nt) {
      int ro = (wn + nt * 16 + l15) * 44 + q * 8;
      float4 x0 = *(const float4*)&Bf[ro];
      float4 x1 = *(const float4*)&Bf[ro + 4];
      split8(x0, x1, Bh[nt], Bl[nt]);
    }
#pragma unroll
    for (int mt = 0; mt < 4; ++mt)
#pragma unroll
      for (int nt = 0; nt < 4; ++nt) {
        acc[mt][nt] = __builtin_amdgcn_mfma_f32_16x16x32_bf16(Ah[mt].b, Bh[nt].b, acc[mt][nt], 0, 0, 0);
        acc[mt][nt] = __builtin_amdgcn_mfma_f32_16x16x32_bf16(Ah[mt].b, Bl[nt].b, acc[mt][nt], 0, 0, 0);
        acc[mt][nt] = __builtin_amdgcn_mfma_f32_16x16x32_bf16(Al[mt].b, Bh[nt].b, acc[mt][nt], 0, 0, 0);
      }
  }

#pragma unroll
  for (int mt = 0; mt < 4; ++mt) {
#pragma unroll
    for (int r = 0; r < 4; ++r) {
      int gi = i0 + wm + mt * 16 + q * 4 + r;
      if (gi >= N_TOTAL) continue;
#pragma unroll
      for (int nt = 0; nt < 4; ++nt)
        atomicAdd(&x[(size_t)gi * D + wn + nt * 16 + l15], acc[mt][nt][r]);
    }
  }
}

// ---------------- K2: BatchNorm + pre-split bf16 planes (unchanged) ----------------
__global__ __launch_bounds__(128) void k_bn(const float* __restrict__ x,
                                            const float* __restrict__ b1,
                                            const float* __restrict__ gamma,
                                            const float* __restrict__ beta,
                                            const float* __restrict__ sw,
                                            float* __restrict__ out_final,
                                            float* __restrict__ outf,
                                            u16* __restrict__ Ah, u16* __restrict__ Al,
                                            u16* __restrict__ Bh, u16* __restrict__ Bl) {
  const int b = blockIdx.x, c = threadIdx.x;
  const float bias = b1[c];
  float s = 0.f, s2 = 0.f;
  const float* xp = x + (size_t)b * BS_BN * D + c;
  for (int r = 0; r < BS_BN; ++r) {
    float v = xp[(size_t)r * D] + bias;
    s += v; s2 = fmaf(v, v, s2);
  }
  float mean = s * (1.f / BS_BN);
  float var = s2 * (1.f / BS_BN) - mean * mean;
  float scale = gamma[c] * rsqrtf(var + 1e-5f);
  float shift = beta[c] - mean * scale;
  float swc = sw[c];
  float* op  = out_final + (size_t)b * BS_BN * D + c;
  float* ofp = outf + (size_t)b * BS_BN * D + c;
  for (int r = 0; r < BS_BN; ++r) {
    float v = fmaf(xp[(size_t)r * D] + bias, scale, shift);
    op[(size_t)r * D] = v;
    ofp[(size_t)r * D] = v;
    int j = b * BS_BN + r;
    size_t rowo = (size_t)j * D;
    int cs = c ^ ((j & 7) << 3);
    uint vb = __float_as_uint(v);
    float vl = v - __uint_as_float(vb & 0xFFFF0000u);
    Ah[rowo + c] = (u16)(vb >> 16);
    Al[rowo + c] = (u16)(__float_as_uint(vl) >> 16);
    float w = v * swc;
    uint wb = __float_as_uint(w);
    float wl = w - __uint_as_float(wb & 0xFFFF0000u);
    Bh[rowo + cs] = (u16)(wb >> 16);
    Bl[rowo + cs] = (u16)(__float_as_uint(wl) >> 16);
  }
}

// ---------------- K2b: a[i] = sum_k sw[k]*out[i,k]^2 (unchanged, proven) ----------------
__global__ __launch_bounds__(256) void k_arow(const float* __restrict__ outf,
                                              const float* __restrict__ sw,
                                              float* __restrict__ aarr) {
  const int t = threadIdx.x;
  const int lane = t & 63;
  const int row = blockIdx.x * 4 + (t >> 6);
  float o1 = outf[(size_t)row * D + lane];
  float o2 = outf[(size_t)row * D + 64 + lane];
  float v = sw[lane] * o1 * o1 + sw[64 + lane] * o2 * o2;
#pragma unroll
  for (int off = 32; off >= 1; off >>= 1) v += __shfl_xor(v, off);
  if (lane == 0) aarr[row] = v;
}

// ---------------- K3: fused score + exact streaming top-50 ----------------
#define FCAP 248
#define FTRIG 120
#define JT 128
#define NT 79

// Bitonic-256 descending sort, 4 regs/lane. FULLY STATIC: both network loops are
// exponent loops with compile-time trip counts so every v[] index is a literal
// after unrolling (rule #20: runtime-indexed arrays go to scratch — the previous
// version's runtime `jj` loop forced v[] into scratch: 760 MB of spill traffic).
__device__ __forceinline__ void sort256_desc(ull v[4], int lane) {
#pragma unroll
  for (int kb = 1; kb <= 8; ++kb) {
    const uint k = 1u << kb;
#pragma unroll
    for (int jb = kb - 1; jb >= 0; --jb) {
      const uint jj = 1u << jb;
      if (jj >= 64) {
        const int sj = (int)(jj >> 6);
#pragma unroll
        for (int s = 0; s < 4; ++s) {
          if (!(s & sj)) {
            const int sp = s | sj;
            const bool up = (((uint)(s * 64) & k) == 0u);
            ull a = v[s], b = v[sp];
            ull mx = a > b ? a : b, mn = a > b ? b : a;
            v[s] = up ? mx : mn;
            v[sp] = up ? mn : mx;
          }
        }
      } else {
#pragma unroll
        for (int s = 0; s < 4; ++s) {
          ull o = __shfl_xor(v[s], (int)jj, 64);
          bool up = (((uint)(s * 64 + lane) & k) == 0u);
          bool lower = (((uint)lane & jj) == 0u);
          ull mx = v[s] > o ? v[s] : o;
          ull mn = v[s] > o ? o : v[s];
          v[s] = (up == lower) ? mx : mn;
        }
      }
    }
  }
}

__global__ __launch_bounds__(1024) void k_fused(const u16* __restrict__ Ah,
                                                const u16* __restrict__ Al,
                                                const u16* __restrict__ Bh,
                                                const u16* __restrict__ Bl,
                                                const float* __restrict__ aarr,
                                                const float* __restrict__ sbp,
                                                ull* __restrict__ lists) {
  __shared__ ull resK[32][FCAP];            // 63.5 KB reservoir
  __shared__ ull thrK[32];
  __shared__ uint cntK[32];
  __shared__ alignas(16) u16 Bls[2 * JT * D];  // 64 KB: [plane][row][col(swz)]

  const int t = threadIdx.x;
  const int lane = t & 63, wid = t >> 6;
  const int q = lane >> 4, l15 = lane & 15;
  const int ifr = wid >> 3, jfr = wid & 7;
  const int i0 = blockIdx.x * 32;
  const float sb = sbp[0];

  if (t < 32) { cntK[t] = 0u; thrK[t] = 0ULL; }

  // A fragments (hi/lo) -> registers, 16B loads from linear planes
  int arow = i0 + ifr * 16 + l15; if (arow > N_TOTAL - 1) arow = N_TOTAL - 1;
  uint4 AhR[4], AlR[4];
#pragma unroll
  for (int kk = 0; kk < 4; ++kk) {
    AhR[kk] = *(const uint4*)(Ah + (size_t)arow * D + kk * 32 + q * 8);
    AlR[kk] = *(const uint4*)(Al + (size_t)arow * D + kk * 32 + q * 8);
  }
  float ai[4];
#pragma unroll
  for (int r = 0; r < 4; ++r) {
    int ig = i0 + ifr * 16 + q * 4 + r; if (ig > N_TOTAL - 1) ig = N_TOTAL - 1;
    ai[r] = aarr[ig] + sb;
  }

  const int jl = jfr * 16 + l15;          // 0..127
  const int swz = (jl & 7) << 4;          // byte-XOR for swizzled B reads

  // prefetch tile 0 into regs
  uint4 stg[4];
#pragma unroll
  for (int s = 0; s < 4; ++s) {
    int idx = s * 1024 + t;
    int p = idx >> 11;
    int off = (idx & 2047) * 16;
    int jg = (off >> 8); if (jg > N_TOTAL - 1) jg = N_TOTAL - 1;
    stg[s] = *(const uint4*)((const char*)(p ? Bl : Bh) + (size_t)jg * 256 + (off & 255));
  }

  for (int tile = 0; tile < NT; ++tile) {
    // compaction check on state after previous tile (skip tile 0)
    if (tile > 0) {
#pragma unroll
      for (int rr = 0; rr < 2; ++rr) {
        int rI = wid + rr * 16;
        uint c = cntK[rI];
        if (c > FTRIG) {
          int cc = (c > (uint)FCAP) ? FCAP : (int)c;
          ull v[4];
#pragma unroll
          for (int s = 0; s < 4; ++s) {
            int g = s * 64 + lane;
            v[s] = (g < cc) ? resK[rI][g] : 0ULL;
          }
          sort256_desc(v, lane);
          if (lane < TOPK) resK[rI][lane] = v[0];
          if (lane == TOPK - 1) thrK[rI] = v[0];
          if (lane == 0) cntK[rI] = TOPK;
        }
      }
    }
    // stage tile's data (prefetched last iter) into LDS
#pragma unroll
    for (int s = 0; s < 4; ++s) {
      int idx = s * 1024 + t;
      int off = (idx & 2047) * 16;
      *(uint4*)((char*)Bls + (idx >> 11) * 32768 + off) = stg[s];
    }
    __syncthreads();  // B1: staged B + compaction thr updates visible

    // prefetch next tile (latency hidden under compute)
    if (tile + 1 < NT) {
      int jb2 = (tile + 1) * JT;
#pragma unroll
      for (int s = 0; s < 4; ++s) {
        int idx = s * 1024 + t;
        int p = idx >> 11;
        int off = (idx & 2047) * 16;
        int jg = jb2 + (off >> 8); if (jg > N_TOTAL - 1) jg = N_TOTAL - 1;
        stg[s] = *(const uint4*)((const char*)(p ? Bl : Bh) + (size_t)jg * 256 + (off & 255));
      }
    }

    const int jb = tile * JT;
    const int jc = jb + jl;
    float ajv = aarr[jc < N_TOTAL ? jc : N_TOTAL - 1];

    // MFMA: same operand order as proven k_score (AhBh, AhBl, AlBh per k-step)
    f32x4 acc = (f32x4){0.f, 0.f, 0.f, 0.f};
    const char* bbase = (const char*)Bls + (size_t)jl * 256;
#pragma unroll
    for (int kk = 0; kk < 4; ++kk) {
      int bo = ((kk * 32 + q * 8) * 2) ^ swz;
      U16 bh, bl, ah, al;
      bh.u = *(const uint4*)(bbase + bo);
      bl.u = *(const uint4*)(bbase + 32768 + bo);
      ah.u = AhR[kk]; al.u = AlR[kk];
      acc = __builtin_amdgcn_mfma_f32_16x16x32_bf16(ah.b, bh.b, acc, 0, 0, 0);
      acc = __builtin_amdgcn_mfma_f32_16x16x32_bf16(ah.b, bl.b, acc, 0, 0, 0);
      acc = __builtin_amdgcn_mfma_f32_16x16x32_bf16(al.b, bh.b, acc, 0, 0, 0);
    }

    // filter into reservoir
    if (jc < N_TOTAL) {
#pragma unroll
      for (int r = 0; r < 4; ++r) {
        int il = ifr * 16 + q * 4 + r;
        float sc = ai[r] + ajv - 2.f * acc[r];
        sc = (sc > 0.f) ? sc : 0.f;
        ull key = ((ull)__float_as_uint(sc) << 32) | (ull)(0xFFFFFFFFu - (uint)jc);
        if (key > thrK[il]) {
          uint pos = atomicAdd(&cntK[il], 1u);
          if (pos < (uint)FCAP) resK[il][pos] = key;
        }
      }
    }
    __syncthreads();  // B2: inserts visible to next compaction check
  }

  // final exact top-50 per row -> lists
#pragma unroll
  for (int rr = 0; rr < 2; ++rr) {
    int rI = wid + rr * 16;
    int ig = i0 + rI;
    uint c = cntK[rI];
    int cc = (c > (uint)FCAP) ? FCAP : (int)c;
    ull v[4];
#pragma unroll
    for (int s = 0; s < 4; ++s) {
      int g = s * 64 + lane;
      v[s] = (g < cc) ? resK[rI][g] : 0ULL;
    }
    sort256_desc(v, lane);
    if (ig < N_TOTAL && lane < TOPK) lists[(size_t)ig * TOPK + lane] = v[0];
  }
}

// ---------------- K4: softmax + sparse write of S (single HBM pass over S) ----------------
__global__ __launch_bounds__(256) void k_write(const ull* __restrict__ lists,
                                               float* __restrict__ S) {
  const int t = threadIdx.x;
  const int lane = t & 63, wid = t >> 6;
  const int row = blockIdx.x * 4 + wid;

  ull key = (lane < TOPK) ? lists[(size_t)row * TOPK + lane] : 0ULL;
  float xv = (lane < TOPK) ? __uint_as_float((uint)(key >> 32)) : -1e30f;
  float mx = xv;
#pragma unroll
  for (int off = 32; off >= 1; off >>= 1) mx = fmaxf(mx, __shfl_xor(mx, off));
  float e = (lane < TOPK) ? expf(xv - mx) : 0.f;
  float ss = e;
#pragma unroll
  for (int off = 32; off >= 1; off >>= 1) ss += __shfl_xor(ss, off);
  float sv = e / ss;
  uint j = 0xFFFFFFFFu - (uint)(key & 0xFFFFFFFFu);

  float4* wp = (float4*)(S + (size_t)row * N_TOTAL);
  float4 z = make_float4(0.f, 0.f, 0.f, 0.f);
  for (int c = lane; c < N_TOTAL / 4; c += 64) wp[c] = z;
  __syncthreads();  // drain zero-stores before scatter (same-address ordering)
  if (lane < TOPK) S[(size_t)row * N_TOTAL + j] = sv;
}

extern "C" void kernel_launch(void* const* d_in, const int* in_sizes, int n_in,
                              void* d_out, int out_size, void* d_ws, size_t ws_size,
                              hipStream_t stream) {
  const float* in    = (const float*)d_in[0];
  const float* W1    = (const float*)d_in[1];
  const float* b1    = (const float*)d_in[2];
  const float* gamma = (const float*)d_in[3];
  const float* beta  = (const float*)d_in[4];
  const float* sw    = (const float*)d_in[5];
  const float* sb    = (const float*)d_in[6];
  float* out_f = (float*)d_out;
  float* S = out_f + (size_t)N_TOTAL * D;  // [10000,10000]

  // ws layout (~24.6 MB)
  float* wsf  = (float*)d_ws;
  float* x    = wsf;                               // 1,280,000 f
  float* outf = wsf + 1280000;                     // 1,280,000 f
  float* aarr = wsf + 2560000;                     // 10,000 f
  u16* Ah = (u16*)(wsf + 2570000);                 // 1,280,000 u16 each
  u16* Al = Ah + 1280000;
  u16* Bh = Al + 1280000;
  u16* Bl = Bh + 1280000;
  ull* lists = (ull*)(Bl + 1280000);               // 10000*50 u64 = 4 MB

  hipMemsetAsync(x, 0, (size_t)N_TOTAL * D * sizeof(float), stream);
  k_gemm1<<<dim3(79, 4), 256, 0, stream>>>(in, W1, x);
  k_bn<<<100, 128, 0, stream>>>(x, b1, gamma, beta, sw, out_f, outf, Ah, Al, Bh, Bl);
  k_arow<<<2500, 256, 0, stream>>>(outf, sw, aarr);
  k_fused<<<313, 1024, 0, stream>>>(Ah, Al, Bh, Bl, aarr, sb, lists);
  k_write<<<2500, 256, 0, stream>>>(lists, S);
}

// Round 3
// 1346.234 us; speedup vs baseline: 1.2837x; 1.2815x over previous
//
#include <hip/hip_runtime.h>
#include <cstdint>

#define N_TOTAL 10000
#define D 128
#define FEAT 3072
#define BS_BN 100
#define TOPK 50

typedef unsigned int uint;
typedef unsigned long long ull;
typedef unsigned short u16;
typedef short short8 __attribute__((ext_vector_type(8)));
typedef float f32x4 __attribute__((ext_vector_type(4)));
union U16 { uint4 u; short8 b; };

// Split fp32 -> bf16 hi (truncate) + bf16 lo (truncate of residual), 8 at a time.
__device__ inline void split8(float4 f0, float4 f1, U16& h, U16& l) {
  float f[8] = {f0.x, f0.y, f0.z, f0.w, f1.x, f1.y, f1.z, f1.w};
  uint hb[8], lb[8];
#pragma unroll
  for (int e = 0; e < 8; ++e) {
    uint b = __float_as_uint(f[e]);
    uint hx = b & 0xFFFF0000u;
    float lf = f[e] - __uint_as_float(hx);
    hb[e] = b >> 16;
    lb[e] = __float_as_uint(lf) >> 16;
  }
  h.u = make_uint4(hb[0] | (hb[1] << 16), hb[2] | (hb[3] << 16),
                   hb[4] | (hb[5] << 16), hb[6] | (hb[7] << 16));
  l.u = make_uint4(lb[0] | (lb[1] << 16), lb[2] | (lb[3] << 16),
                   lb[4] | (lb[5] << 16), lb[6] | (lb[7] << 16));
}

// ---------------- K1: x = in @ W1^T via split-bf16 MFMA (unchanged, proven) ----------------
__global__ __launch_bounds__(256) void k_gemm1(const float* __restrict__ in,
                                               const float* __restrict__ W1,
                                               float* __restrict__ x) {
  __shared__ alignas(16) float Af[128 * 44];
  __shared__ alignas(16) float Bf[128 * 44];
  const int t = threadIdx.x;
  const int lane = t & 63, wid = t >> 6;
  const int q = lane >> 4, l15 = lane & 15;
  const int i0 = blockIdx.x * 128;
  const int k0 = blockIdx.y * 768;
  const int wm = (wid & 1) * 64, wn = (wid >> 1) * 64;

  f32x4 acc[4][4];
#pragma unroll
  for (int mt = 0; mt < 4; ++mt)
#pragma unroll
    for (int nt = 0; nt < 4; ++nt) acc[mt][nt] = (f32x4){0.f, 0.f, 0.f, 0.f};

  for (int kb = k0; kb < k0 + 768; kb += 32) {
    __syncthreads();
#pragma unroll
    for (int s = 0; s < 4; ++s) {
      int idx = t + 256 * s;
      int row = idx >> 3, f4 = (idx & 7) * 4;
      int gi = i0 + row; if (gi > N_TOTAL - 1) gi = N_TOTAL - 1;
      *(float4*)&Af[row * 44 + f4] = *(const float4*)&in[(size_t)gi * FEAT + kb + f4];
      *(float4*)&Bf[row * 44 + f4] = *(const float4*)&W1[(size_t)row * FEAT + kb + f4];
    }
    __syncthreads();
    U16 Ah[4], Al[4], Bh[4], Bl[4];
#pragma unroll
    for (int mt = 0; mt < 4; ++mt) {
      int ro = (wm + mt * 16 + l15) * 44 + q * 8;
      float4 x0 = *(const float4*)&Af[ro];
      float4 x1 = *(const float4*)&Af[ro + 4];
      split8(x0, x1, Ah[mt], Al[mt]);
    }
#pragma unroll
    for (int nt = 0; nt < 4; ++nt) {
      int ro = (wn + nt * 16 + l15) * 44 + q * 8;
      float4 x0 = *(const float4*)&Bf[ro];
      float4 x1 = *(const float4*)&Bf[ro + 4];
      split8(x0, x1, Bh[nt], Bl[nt]);
    }
#pragma unroll
    for (int mt = 0; mt < 4; ++mt)
#pragma unroll
      for (int nt = 0; nt < 4; ++nt) {
        acc[mt][nt] = __builtin_amdgcn_mfma_f32_16x16x32_bf16(Ah[mt].b, Bh[nt].b, acc[mt][nt], 0, 0, 0);
        acc[mt][nt] = __builtin_amdgcn_mfma_f32_16x16x32_bf16(Ah[mt].b, Bl[nt].b, acc[mt][nt], 0, 0, 0);
        acc[mt][nt] = __builtin_amdgcn_mfma_f32_16x16x32_bf16(Al[mt].b, Bh[nt].b, acc[mt][nt], 0, 0, 0);
      }
  }

#pragma unroll
  for (int mt = 0; mt < 4; ++mt) {
#pragma unroll
    for (int r = 0; r < 4; ++r) {
      int gi = i0 + wm + mt * 16 + q * 4 + r;
      if (gi >= N_TOTAL) continue;
#pragma unroll
      for (int nt = 0; nt < 4; ++nt)
        atomicAdd(&x[(size_t)gi * D + wn + nt * 16 + l15], acc[mt][nt][r]);
    }
  }
}

// ---------------- K2: BatchNorm + pre-split bf16 planes (unchanged) ----------------
__global__ __launch_bounds__(128) void k_bn(const float* __restrict__ x,
                                            const float* __restrict__ b1,
                                            const float* __restrict__ gamma,
                                            const float* __restrict__ beta,
                                            const float* __restrict__ sw,
                                            float* __restrict__ out_final,
                                            float* __restrict__ outf,
                                            u16* __restrict__ Ah, u16* __restrict__ Al,
                                            u16* __restrict__ Bh, u16* __restrict__ Bl) {
  const int b = blockIdx.x, c = threadIdx.x;
  const float bias = b1[c];
  float s = 0.f, s2 = 0.f;
  const float* xp = x + (size_t)b * BS_BN * D + c;
  for (int r = 0; r < BS_BN; ++r) {
    float v = xp[(size_t)r * D] + bias;
    s += v; s2 = fmaf(v, v, s2);
  }
  float mean = s * (1.f / BS_BN);
  float var = s2 * (1.f / BS_BN) - mean * mean;
  float scale = gamma[c] * rsqrtf(var + 1e-5f);
  float shift = beta[c] - mean * scale;
  float swc = sw[c];
  float* op  = out_final + (size_t)b * BS_BN * D + c;
  float* ofp = outf + (size_t)b * BS_BN * D + c;
  for (int r = 0; r < BS_BN; ++r) {
    float v = fmaf(xp[(size_t)r * D] + bias, scale, shift);
    op[(size_t)r * D] = v;
    ofp[(size_t)r * D] = v;
    int j = b * BS_BN + r;
    size_t rowo = (size_t)j * D;
    int cs = c ^ ((j & 7) << 3);
    uint vb = __float_as_uint(v);
    float vl = v - __uint_as_float(vb & 0xFFFF0000u);
    Ah[rowo + c] = (u16)(vb >> 16);
    Al[rowo + c] = (u16)(__float_as_uint(vl) >> 16);
    float w = v * swc;
    uint wb = __float_as_uint(w);
    float wl = w - __uint_as_float(wb & 0xFFFF0000u);
    Bh[rowo + cs] = (u16)(wb >> 16);
    Bl[rowo + cs] = (u16)(__float_as_uint(wl) >> 16);
  }
}

// ---------------- K2b: a[i] = sum_k sw[k]*out[i,k]^2 (unchanged, proven) ----------------
__global__ __launch_bounds__(256) void k_arow(const float* __restrict__ outf,
                                              const float* __restrict__ sw,
                                              float* __restrict__ aarr) {
  const int t = threadIdx.x;
  const int lane = t & 63;
  const int row = blockIdx.x * 4 + (t >> 6);
  float o1 = outf[(size_t)row * D + lane];
  float o2 = outf[(size_t)row * D + 64 + lane];
  float v = sw[lane] * o1 * o1 + sw[64 + lane] * o2 * o2;
#pragma unroll
  for (int off = 32; off >= 1; off >>= 1) v += __shfl_xor(v, off);
  if (lane == 0) aarr[row] = v;
}

// ---------------- K3: fused score + exact streaming top-50 ----------------
// NO thread-local arrays, NO 64-bit shuffle templates anywhere in this kernel:
// round-1/2 showed 52 VGPRs + ~800 MB phantom scratch traffic (time = bytes/BW).
// All private state is named scalars; sort is a constexpr-template bitonic network
// on four named ull regs with hand-split 2x32-bit shuffles.
#define FCAP 248
#define FTRIG 120
#define JT 128
#define NT 79

__device__ __forceinline__ ull shfl64(ull x, int m) {
  int lo = __shfl_xor((int)(uint)x, m, 64);
  int hi = __shfl_xor((int)(uint)(x >> 32), m, 64);
  return ((ull)(uint)hi << 32) | (ull)(uint)lo;
}
__device__ __forceinline__ void cswap(ull& a, ull& b, bool up) {
  ull mx = a > b ? a : b;
  ull mn = a > b ? b : a;
  a = up ? mx : mn;
  b = up ? mn : mx;
}
template <uint K>
__device__ __forceinline__ void bmerge(ull& v0, ull& v1, ull& v2, ull& v3, int lane) {
  constexpr bool c0 = ((0u & K) == 0u);
  constexpr bool c1 = ((64u & K) == 0u);
  constexpr bool c2 = ((128u & K) == 0u);
  constexpr bool c3 = ((192u & K) == 0u);
  if constexpr (K > 128) { cswap(v0, v2, c0); cswap(v1, v3, c1); }
  if constexpr (K > 64)  { cswap(v0, v1, c0); cswap(v2, v3, c2); }
  bool u0, u1, u2, u3;
  if constexpr (K <= 32) {
    bool u = (((uint)lane & K) == 0u);
    u0 = u; u1 = u; u2 = u; u3 = u;
  } else {
    u0 = c0; u1 = c1; u2 = c2; u3 = c3;
  }
  constexpr uint JSTART = (K > 64) ? 32u : (K >> 1);
#pragma unroll
  for (uint jj = JSTART; jj >= 1u; jj >>= 1) {
    bool low = (((uint)lane & jj) == 0u);
    { ull o = shfl64(v0, (int)jj); v0 = ((u0 == low) ? (v0 > o ? v0 : o) : (v0 > o ? o : v0)); }
    { ull o = shfl64(v1, (int)jj); v1 = ((u1 == low) ? (v1 > o ? v1 : o) : (v1 > o ? o : v1)); }
    { ull o = shfl64(v2, (int)jj); v2 = ((u2 == low) ? (v2 > o ? v2 : o) : (v2 > o ? o : v2)); }
    { ull o = shfl64(v3, (int)jj); v3 = ((u3 == low) ? (v3 > o ? v3 : o) : (v3 > o ? o : v3)); }
  }
}
__device__ __forceinline__ void sort256n(ull& v0, ull& v1, ull& v2, ull& v3, int lane) {
  bmerge<2>(v0, v1, v2, v3, lane);
  bmerge<4>(v0, v1, v2, v3, lane);
  bmerge<8>(v0, v1, v2, v3, lane);
  bmerge<16>(v0, v1, v2, v3, lane);
  bmerge<32>(v0, v1, v2, v3, lane);
  bmerge<64>(v0, v1, v2, v3, lane);
  bmerge<128>(v0, v1, v2, v3, lane);
  bmerge<256>(v0, v1, v2, v3, lane);
}

// prefetch one 16B chunk (sdx literal 0..3) of tile starting at column jbase
#define PREF(sdx, dst, jbase) {                                                   \
    int idx_ = (sdx) * 1024 + t;                                                  \
    int p_ = idx_ >> 11;                                                          \
    int off_ = (idx_ & 2047) * 16;                                                \
    int jg_ = (jbase) + (off_ >> 8); if (jg_ > N_TOTAL - 1) jg_ = N_TOTAL - 1;    \
    dst = *(const uint4*)((const char*)(p_ ? Bl : Bh) + (size_t)jg_ * 256 + (off_ & 255)); }

#define STG(sdx, src) {                                                           \
    int idx_ = (sdx) * 1024 + t;                                                  \
    int off_ = (idx_ & 2047) * 16;                                                \
    *(uint4*)((char*)Bls + (idx_ >> 11) * 32768 + off_) = src; }

#define MM(kk, AH, AL) {                                                          \
    int bo_ = (((kk) * 32 + q * 8) * 2) ^ swz;                                    \
    U16 bh_, bl_, ah_, al_;                                                       \
    bh_.u = *(const uint4*)(bbase + bo_);                                         \
    bl_.u = *(const uint4*)(bbase + 32768 + bo_);                                 \
    ah_.u = AH; al_.u = AL;                                                       \
    acc = __builtin_amdgcn_mfma_f32_16x16x32_bf16(ah_.b, bh_.b, acc, 0, 0, 0);    \
    acc = __builtin_amdgcn_mfma_f32_16x16x32_bf16(ah_.b, bl_.b, acc, 0, 0, 0);    \
    acc = __builtin_amdgcn_mfma_f32_16x16x32_bf16(al_.b, bh_.b, acc, 0, 0, 0); }

#define FILT(r, AIr) {                                                            \
    int il_ = ifr * 16 + q * 4 + (r);                                             \
    float sc_ = (AIr) + ajv - 2.f * acc[r];                                       \
    sc_ = (sc_ > 0.f) ? sc_ : 0.f;                                                \
    ull key_ = ((ull)__float_as_uint(sc_) << 32) | (ull)(0xFFFFFFFFu - (uint)jc); \
    if (key_ > thrK[il_]) {                                                       \
      uint pos_ = atomicAdd(&cntK[il_], 1u);                                      \
      if (pos_ < (uint)FCAP) resK[il_][pos_] = key_;                              \
    } }

#define COMPACT(rI, writeback) {                                                  \
    int cc_ = ((int)c > FCAP) ? FCAP : (int)c;                                    \
    ull v0 = (lane < cc_) ? resK[rI][lane] : 0ULL;                                \
    ull v1 = (64 + lane < cc_) ? resK[rI][64 + lane] : 0ULL;                      \
    ull v2 = (128 + lane < cc_) ? resK[rI][128 + lane] : 0ULL;                    \
    ull v3 = (192 + lane < cc_) ? resK[rI][192 + lane] : 0ULL;                    \
    sort256n(v0, v1, v2, v3, lane);                                               \
    writeback }

__global__ __launch_bounds__(1024, 4) void k_fused(const u16* __restrict__ Ah,
                                                   const u16* __restrict__ Al,
                                                   const u16* __restrict__ Bh,
                                                   const u16* __restrict__ Bl,
                                                   const float* __restrict__ aarr,
                                                   const float* __restrict__ sbp,
                                                   ull* __restrict__ lists) {
  __shared__ ull resK[32][FCAP];            // 63.5 KB reservoir
  __shared__ ull thrK[32];
  __shared__ uint cntK[32];
  __shared__ alignas(16) u16 Bls[2 * JT * D];  // 64 KB: [plane][row][col(swz)]

  const int t = threadIdx.x;
  const int lane = t & 63, wid = t >> 6;
  const int q = lane >> 4, l15 = lane & 15;
  const int ifr = wid >> 3, jfr = wid & 7;
  const int i0 = blockIdx.x * 32;
  const float sb = sbp[0];

  if (t < 32) { cntK[t] = 0u; thrK[t] = 0ULL; }

  // A fragments (hi/lo) -> named registers, 16B loads from linear planes
  int arow = i0 + ifr * 16 + l15; if (arow > N_TOTAL - 1) arow = N_TOTAL - 1;
  const u16* apH = Ah + (size_t)arow * D + q * 8;
  const u16* apL = Al + (size_t)arow * D + q * 8;
  uint4 Ah0 = *(const uint4*)(apH);
  uint4 Ah1 = *(const uint4*)(apH + 32);
  uint4 Ah2 = *(const uint4*)(apH + 64);
  uint4 Ah3 = *(const uint4*)(apH + 96);
  uint4 Al0 = *(const uint4*)(apL);
  uint4 Al1 = *(const uint4*)(apL + 32);
  uint4 Al2 = *(const uint4*)(apL + 64);
  uint4 Al3 = *(const uint4*)(apL + 96);

  int ig0 = i0 + ifr * 16 + q * 4;
  int igc0 = ig0 + 0; if (igc0 > N_TOTAL - 1) igc0 = N_TOTAL - 1;
  int igc1 = ig0 + 1; if (igc1 > N_TOTAL - 1) igc1 = N_TOTAL - 1;
  int igc2 = ig0 + 2; if (igc2 > N_TOTAL - 1) igc2 = N_TOTAL - 1;
  int igc3 = ig0 + 3; if (igc3 > N_TOTAL - 1) igc3 = N_TOTAL - 1;
  const float ai0 = aarr[igc0] + sb;
  const float ai1 = aarr[igc1] + sb;
  const float ai2 = aarr[igc2] + sb;
  const float ai3 = aarr[igc3] + sb;

  const int jl = jfr * 16 + l15;          // 0..127
  const int swz = (jl & 7) << 4;          // byte-XOR for swizzled B reads

  // prefetch tile 0 into named regs
  uint4 stg0, stg1, stg2, stg3;
  PREF(0, stg0, 0) PREF(1, stg1, 0) PREF(2, stg2, 0) PREF(3, stg3, 0)

  for (int tile = 0; tile < NT; ++tile) {
    // compaction check on state after previous tile (skip tile 0)
    if (tile > 0) {
      {
        int rI = wid;
        uint c = cntK[rI];
        if (c > FTRIG) {
          COMPACT(rI,
            if (lane < TOPK) resK[rI][lane] = v0;
            if (lane == TOPK - 1) thrK[rI] = v0;
            if (lane == 0) cntK[rI] = TOPK;)
        }
      }
      {
        int rI = wid + 16;
        uint c = cntK[rI];
        if (c > FTRIG) {
          COMPACT(rI,
            if (lane < TOPK) resK[rI][lane] = v0;
            if (lane == TOPK - 1) thrK[rI] = v0;
            if (lane == 0) cntK[rI] = TOPK;)
        }
      }
    }
    // stage tile's data (prefetched last iter) into LDS
    STG(0, stg0) STG(1, stg1) STG(2, stg2) STG(3, stg3)
    __syncthreads();  // B1: staged B + compaction thr updates visible

    // prefetch next tile (latency hidden under compute)
    if (tile + 1 < NT) {
      int jb2 = (tile + 1) * JT;
      PREF(0, stg0, jb2) PREF(1, stg1, jb2) PREF(2, stg2, jb2) PREF(3, stg3, jb2)
    }

    const int jb = tile * JT;
    const int jc = jb + jl;
    float ajv = aarr[jc < N_TOTAL ? jc : N_TOTAL - 1];

    // MFMA: same operand order as proven k_score (AhBh, AhBl, AlBh per k-step)
    f32x4 acc = (f32x4){0.f, 0.f, 0.f, 0.f};
    const char* bbase = (const char*)Bls + (size_t)jl * 256;
    MM(0, Ah0, Al0) MM(1, Ah1, Al1) MM(2, Ah2, Al2) MM(3, Ah3, Al3)

    // filter into reservoir
    if (jc < N_TOTAL) {
      FILT(0, ai0) FILT(1, ai1) FILT(2, ai2) FILT(3, ai3)
    }
    __syncthreads();  // B2: inserts visible to next compaction check
  }

  // final exact top-50 per row -> lists
  {
    int rI = wid;
    int ig = i0 + rI;
    uint c = cntK[rI];
    COMPACT(rI,
      if (ig < N_TOTAL && lane < TOPK) lists[(size_t)ig * TOPK + lane] = v0;)
  }
  {
    int rI = wid + 16;
    int ig = i0 + rI;
    uint c = cntK[rI];
    COMPACT(rI,
      if (ig < N_TOTAL && lane < TOPK) lists[(size_t)ig * TOPK + lane] = v0;)
  }
}

// ---------------- K4: softmax + sparse write of S (single HBM pass over S) ----------------
__global__ __launch_bounds__(256) void k_write(const ull* __restrict__ lists,
                                               float* __restrict__ S) {
  const int t = threadIdx.x;
  const int lane = t & 63, wid = t >> 6;
  const int row = blockIdx.x * 4 + wid;

  ull key = (lane < TOPK) ? lists[(size_t)row * TOPK + lane] : 0ULL;
  float xv = (lane < TOPK) ? __uint_as_float((uint)(key >> 32)) : -1e30f;
  float mx = xv;
#pragma unroll
  for (int off = 32; off >= 1; off >>= 1) mx = fmaxf(mx, __shfl_xor(mx, off));
  float e = (lane < TOPK) ? expf(xv - mx) : 0.f;
  float ss = e;
#pragma unroll
  for (int off = 32; off >= 1; off >>= 1) ss += __shfl_xor(ss, off);
  float sv = e / ss;
  uint j = 0xFFFFFFFFu - (uint)(key & 0xFFFFFFFFu);

  float4* wp = (float4*)(S + (size_t)row * N_TOTAL);
  float4 z = make_float4(0.f, 0.f, 0.f, 0.f);
  for (int c = lane; c < N_TOTAL / 4; c += 64) wp[c] = z;
  __syncthreads();  // drain zero-stores before scatter (same-address ordering)
  if (lane < TOPK) S[(size_t)row * N_TOTAL + j] = sv;
}

extern "C" void kernel_launch(void* const* d_in, const int* in_sizes, int n_in,
                              void* d_out, int out_size, void* d_ws, size_t ws_size,
                              hipStream_t stream) {
  const float* in    = (const float*)d_in[0];
  const float* W1    = (const float*)d_in[1];
  const float* b1    = (const float*)d_in[2];
  const float* gamma = (const float*)d_in[3];
  const float* beta  = (const float*)d_in[4];
  const float* sw    = (const float*)d_in[5];
  const float* sb    = (const float*)d_in[6];
  float* out_f = (float*)d_out;
  float* S = out_f + (size_t)N_TOTAL * D;  // [10000,10000]

  // ws layout (~24.6 MB)
  float* wsf  = (float*)d_ws;
  float* x    = wsf;                               // 1,280,000 f
  float* outf = wsf + 1280000;                     // 1,280,000 f
  float* aarr = wsf + 2560000;                     // 10,000 f
  u16* Ah = (u16*)(wsf + 2570000);                 // 1,280,000 u16 each
  u16* Al = Ah + 1280000;
  u16* Bh = Al + 1280000;
  u16* Bl = Bh + 1280000;
  ull* lists = (ull*)(Bl + 1280000);               // 10000*50 u64 = 4 MB

  hipMemsetAsync(x, 0, (size_t)N_TOTAL * D * sizeof(float), stream);
  k_gemm1<<<dim3(79, 4), 256, 0, stream>>>(in, W1, x);
  k_bn<<<100, 128, 0, stream>>>(x, b1, gamma, beta, sw, out_f, outf, Ah, Al, Bh, Bl);
  k_arow<<<2500, 256, 0, stream>>>(outf, sw, aarr);
  k_fused<<<313, 1024, 0, stream>>>(Ah, Al, Bh, Bl, aarr, sb, lists);
  k_write<<<2500, 256, 0, stream>>>(lists, S);
}

// Round 4
// 1249.311 us; speedup vs baseline: 1.3832x; 1.0776x over previous
//
#include <hip/hip_runtime.h>
#include <cstdint>

#define N_TOTAL 10000
#define D 128
#define FEAT 3072
#define BS_BN 100
#define TOPK 50

typedef unsigned int uint;
typedef unsigned long long ull;
typedef unsigned short u16;
typedef short short8 __attribute__((ext_vector_type(8)));
typedef float f32x4 __attribute__((ext_vector_type(4)));
union U16 { uint4 u; short8 b; };

// Split fp32 -> bf16 hi (truncate) + bf16 lo (truncate of residual), 8 at a time.
__device__ inline void split8(float4 f0, float4 f1, U16& h, U16& l) {
  float f[8] = {f0.x, f0.y, f0.z, f0.w, f1.x, f1.y, f1.z, f1.w};
  uint hb[8], lb[8];
#pragma unroll
  for (int e = 0; e < 8; ++e) {
    uint b = __float_as_uint(f[e]);
    uint hx = b & 0xFFFF0000u;
    float lf = f[e] - __uint_as_float(hx);
    hb[e] = b >> 16;
    lb[e] = __float_as_uint(lf) >> 16;
  }
  h.u = make_uint4(hb[0] | (hb[1] << 16), hb[2] | (hb[3] << 16),
                   hb[4] | (hb[5] << 16), hb[6] | (hb[7] << 16));
  l.u = make_uint4(lb[0] | (lb[1] << 16), lb[2] | (lb[3] << 16),
                   lb[4] | (lb[5] << 16), lb[6] | (lb[7] << 16));
}

// ---------------- K1: x = in @ W1^T via split-bf16 MFMA (unchanged, proven) ----------------
__global__ __launch_bounds__(256) void k_gemm1(const float* __restrict__ in,
                                               const float* __restrict__ W1,
                                               float* __restrict__ x) {
  __shared__ alignas(16) float Af[128 * 44];
  __shared__ alignas(16) float Bf[128 * 44];
  const int t = threadIdx.x;
  const int lane = t & 63, wid = t >> 6;
  const int q = lane >> 4, l15 = lane & 15;
  const int i0 = blockIdx.x * 128;
  const int k0 = blockIdx.y * 768;
  const int wm = (wid & 1) * 64, wn = (wid >> 1) * 64;

  f32x4 acc[4][4];
#pragma unroll
  for (int mt = 0; mt < 4; ++mt)
#pragma unroll
    for (int nt = 0; nt < 4; ++nt) acc[mt][nt] = (f32x4){0.f, 0.f, 0.f, 0.f};

  for (int kb = k0; kb < k0 + 768; kb += 32) {
    __syncthreads();
#pragma unroll
    for (int s = 0; s < 4; ++s) {
      int idx = t + 256 * s;
      int row = idx >> 3, f4 = (idx & 7) * 4;
      int gi = i0 + row; if (gi > N_TOTAL - 1) gi = N_TOTAL - 1;
      *(float4*)&Af[row * 44 + f4] = *(const float4*)&in[(size_t)gi * FEAT + kb + f4];
      *(float4*)&Bf[row * 44 + f4] = *(const float4*)&W1[(size_t)row * FEAT + kb + f4];
    }
    __syncthreads();
    U16 Ah[4], Al[4], Bh[4], Bl[4];
#pragma unroll
    for (int mt = 0; mt < 4; ++mt) {
      int ro = (wm + mt * 16 + l15) * 44 + q * 8;
      float4 x0 = *(const float4*)&Af[ro];
      float4 x1 = *(const float4*)&Af[ro + 4];
      split8(x0, x1, Ah[mt], Al[mt]);
    }
#pragma unroll
    for (int nt = 0; nt < 4; ++nt) {
      int ro = (wn + nt * 16 + l15) * 44 + q * 8;
      float4 x0 = *(const float4*)&Bf[ro];
      float4 x1 = *(const float4*)&Bf[ro + 4];
      split8(x0, x1, Bh[nt], Bl[nt]);
    }
#pragma unroll
    for (int mt = 0; mt < 4; ++mt)
#pragma unroll
      for (int nt = 0; nt < 4; ++nt) {
        acc[mt][nt] = __builtin_amdgcn_mfma_f32_16x16x32_bf16(Ah[mt].b, Bh[nt].b, acc[mt][nt], 0, 0, 0);
        acc[mt][nt] = __builtin_amdgcn_mfma_f32_16x16x32_bf16(Ah[mt].b, Bl[nt].b, acc[mt][nt], 0, 0, 0);
        acc[mt][nt] = __builtin_amdgcn_mfma_f32_16x16x32_bf16(Al[mt].b, Bh[nt].b, acc[mt][nt], 0, 0, 0);
      }
  }

#pragma unroll
  for (int mt = 0; mt < 4; ++mt) {
#pragma unroll
    for (int r = 0; r < 4; ++r) {
      int gi = i0 + wm + mt * 16 + q * 4 + r;
      if (gi >= N_TOTAL) continue;
#pragma unroll
      for (int nt = 0; nt < 4; ++nt)
        atomicAdd(&x[(size_t)gi * D + wn + nt * 16 + l15], acc[mt][nt][r]);
    }
  }
}

// ---------------- K2: BatchNorm + pre-split bf16 planes (unchanged) ----------------
__global__ __launch_bounds__(128) void k_bn(const float* __restrict__ x,
                                            const float* __restrict__ b1,
                                            const float* __restrict__ gamma,
                                            const float* __restrict__ beta,
                                            const float* __restrict__ sw,
                                            float* __restrict__ out_final,
                                            float* __restrict__ outf,
                                            u16* __restrict__ Ah, u16* __restrict__ Al,
                                            u16* __restrict__ Bh, u16* __restrict__ Bl) {
  const int b = blockIdx.x, c = threadIdx.x;
  const float bias = b1[c];
  float s = 0.f, s2 = 0.f;
  const float* xp = x + (size_t)b * BS_BN * D + c;
  for (int r = 0; r < BS_BN; ++r) {
    float v = xp[(size_t)r * D] + bias;
    s += v; s2 = fmaf(v, v, s2);
  }
  float mean = s * (1.f / BS_BN);
  float var = s2 * (1.f / BS_BN) - mean * mean;
  float scale = gamma[c] * rsqrtf(var + 1e-5f);
  float shift = beta[c] - mean * scale;
  float swc = sw[c];
  float* op  = out_final + (size_t)b * BS_BN * D + c;
  float* ofp = outf + (size_t)b * BS_BN * D + c;
  for (int r = 0; r < BS_BN; ++r) {
    float v = fmaf(xp[(size_t)r * D] + bias, scale, shift);
    op[(size_t)r * D] = v;
    ofp[(size_t)r * D] = v;
    int j = b * BS_BN + r;
    size_t rowo = (size_t)j * D;
    int cs = c ^ ((j & 7) << 3);
    uint vb = __float_as_uint(v);
    float vl = v - __uint_as_float(vb & 0xFFFF0000u);
    Ah[rowo + c] = (u16)(vb >> 16);
    Al[rowo + c] = (u16)(__float_as_uint(vl) >> 16);
    float w = v * swc;
    uint wb = __float_as_uint(w);
    float wl = w - __uint_as_float(wb & 0xFFFF0000u);
    Bh[rowo + cs] = (u16)(wb >> 16);
    Bl[rowo + cs] = (u16)(__float_as_uint(wl) >> 16);
  }
}

// ---------------- K2b: a[i] = sum_k sw[k]*out[i,k]^2 (unchanged, proven) ----------------
__global__ __launch_bounds__(256) void k_arow(const float* __restrict__ outf,
                                              const float* __restrict__ sw,
                                              float* __restrict__ aarr) {
  const int t = threadIdx.x;
  const int lane = t & 63;
  const int row = blockIdx.x * 4 + (t >> 6);
  float o1 = outf[(size_t)row * D + lane];
  float o2 = outf[(size_t)row * D + 64 + lane];
  float v = sw[lane] * o1 * o1 + sw[64 + lane] * o2 * o2;
#pragma unroll
  for (int off = 32; off >= 1; off >>= 1) v += __shfl_xor(v, off);
  if (lane == 0) aarr[row] = v;
}

// ---------------- K3: fused score + exact streaming top-50 ----------------
// Round-3 post-mortem: the bitonic sort's __shfl_xor = ds_bpermute (LDS pipe,
// ~120cy latency, 264/sort) saturated the LDS pipe -> 762us with all pipes idle.
// Replaced with ballot-greedy exact select: compares on VALU, ballot/popc on SALU,
// ZERO LDS-pipe ops. Same 64-bit key order -> identical selected set.
#define FCAP 320
#define FTRIG 192
#define JT 128
#define NT 79

// prefetch one 16B chunk (sdx literal 0..3) of tile starting at column jbase
#define PREF(sdx, dst, jbase) {                                                   \
    int idx_ = (sdx) * 1024 + t;                                                  \
    int p_ = idx_ >> 11;                                                          \
    int off_ = (idx_ & 2047) * 16;                                                \
    int jg_ = (jbase) + (off_ >> 8); if (jg_ > N_TOTAL - 1) jg_ = N_TOTAL - 1;    \
    dst = *(const uint4*)((const char*)(p_ ? Bl : Bh) + (size_t)jg_ * 256 + (off_ & 255)); }

#define STG(sdx, src) {                                                           \
    int idx_ = (sdx) * 1024 + t;                                                  \
    int off_ = (idx_ & 2047) * 16;                                                \
    *(uint4*)((char*)Bls + (idx_ >> 11) * 32768 + off_) = src; }

#define MM(kk, AH, AL) {                                                          \
    int bo_ = (((kk) * 32 + q * 8) * 2) ^ swz;                                    \
    U16 bh_, bl_, ah_, al_;                                                       \
    bh_.u = *(const uint4*)(bbase + bo_);                                         \
    bl_.u = *(const uint4*)(bbase + 32768 + bo_);                                 \
    ah_.u = AH; al_.u = AL;                                                       \
    acc = __builtin_amdgcn_mfma_f32_16x16x32_bf16(ah_.b, bh_.b, acc, 0, 0, 0);    \
    acc = __builtin_amdgcn_mfma_f32_16x16x32_bf16(ah_.b, bl_.b, acc, 0, 0, 0);    \
    acc = __builtin_amdgcn_mfma_f32_16x16x32_bf16(al_.b, bh_.b, acc, 0, 0, 0); }

#define FILT(r, AIr) {                                                            \
    int il_ = ifr * 16 + q * 4 + (r);                                             \
    float sc_ = (AIr) + ajv - 2.f * acc[r];                                       \
    sc_ = (sc_ > 0.f) ? sc_ : 0.f;                                                \
    ull key_ = ((ull)__float_as_uint(sc_) << 32) | (ull)(0xFFFFFFFFu - (uint)jc); \
    if (key_ > thrK[il_]) {                                                       \
      uint pos_ = atomicAdd(&cntK[il_], 1u);                                      \
      if (pos_ < (uint)FCAP) resK[il_][pos_] = key_;                              \
    } }

// Exact top-50 select over <=320 unique 64-bit keys held 5-per-lane in registers.
// Phase 1: MSB-greedy max Ts with count(score_bits >= Ts) >= 50 (31 iters).
// Phase 2: among score==Ts ties, MSB-greedy max Ti with count(inv >= Ti) >= need
// (32 iters). Survivors = exactly 50 (keys unique); compact via ballot prefix.
// Zero-padded invalid slots can never pass any predicate (proof: Tt>=1 always;
// real tie invs >= 0xFFFFD8F0 so final Ti >= 1 excludes padding inv=0).
#define SEL50(rI, WB, ...)                                                        \
  {                                                                               \
    int cc_ = ((int)c > FCAP) ? FCAP : (int)c;                                    \
    uint sA_, sB_, sC_, sD_, sE_, iA_, iB_, iC_, iD_, iE_;                        \
    { ull k_ = (lane < cc_) ? resK[rI][lane] : 0ULL;         sA_=(uint)(k_>>32); iA_=(uint)k_; } \
    { ull k_ = (64+lane < cc_) ? resK[rI][64+lane] : 0ULL;   sB_=(uint)(k_>>32); iB_=(uint)k_; } \
    { ull k_ = (128+lane < cc_) ? resK[rI][128+lane] : 0ULL; sC_=(uint)(k_>>32); iC_=(uint)k_; } \
    { ull k_ = (192+lane < cc_) ? resK[rI][192+lane] : 0ULL; sD_=(uint)(k_>>32); iD_=(uint)k_; } \
    { ull k_ = (256+lane < cc_) ? resK[rI][256+lane] : 0ULL; sE_=(uint)(k_>>32); iE_=(uint)k_; } \
    uint Ts_ = 0u;                                                                \
    for (int b_ = 30; b_ >= 0; --b_) {                                            \
      uint Tt_ = Ts_ | (1u << b_);                                                \
      int n_ = __popcll(__ballot(sA_ >= Tt_)) + __popcll(__ballot(sB_ >= Tt_))    \
             + __popcll(__ballot(sC_ >= Tt_)) + __popcll(__ballot(sD_ >= Tt_))    \
             + __popcll(__ballot(sE_ >= Tt_));                                    \
      if (n_ >= TOPK) Ts_ = Tt_;                                                  \
    }                                                                             \
    int c1_ = __popcll(__ballot(sA_ > Ts_)) + __popcll(__ballot(sB_ > Ts_))       \
            + __popcll(__ballot(sC_ > Ts_)) + __popcll(__ballot(sD_ > Ts_))       \
            + __popcll(__ballot(sE_ > Ts_));                                      \
    int need_ = TOPK - c1_;                                                       \
    uint Ti_ = 0u;                                                                \
    for (int b_ = 31; b_ >= 0; --b_) {                                            \
      uint Tt_ = Ti_ | (1u << b_);                                                \
      int n_ = __popcll(__ballot(sA_ == Ts_ && iA_ >= Tt_))                       \
             + __popcll(__ballot(sB_ == Ts_ && iB_ >= Tt_))                       \
             + __popcll(__ballot(sC_ == Ts_ && iC_ >= Tt_))                       \
             + __popcll(__ballot(sD_ == Ts_ && iD_ >= Tt_))                       \
             + __popcll(__ballot(sE_ == Ts_ && iE_ >= Tt_));                      \
      if (n_ >= need_) Ti_ = Tt_;                                                 \
    }                                                                             \
    bool pA_ = (sA_ > Ts_) || (sA_ == Ts_ && iA_ >= Ti_);                         \
    bool pB_ = (sB_ > Ts_) || (sB_ == Ts_ && iB_ >= Ti_);                         \
    bool pC_ = (sC_ > Ts_) || (sC_ == Ts_ && iC_ >= Ti_);                         \
    bool pD_ = (sD_ > Ts_) || (sD_ == Ts_ && iD_ >= Ti_);                         \
    bool pE_ = (sE_ > Ts_) || (sE_ == Ts_ && iE_ >= Ti_);                         \
    ull bA_ = __ballot(pA_), bB_ = __ballot(pB_), bC_ = __ballot(pC_);            \
    ull bD_ = __ballot(pD_), bE_ = __ballot(pE_);                                 \
    ull lt_ = (1ull << lane) - 1ull;                                              \
    int oB_ = __popcll(bA_);                                                      \
    int oC_ = oB_ + __popcll(bB_);                                                \
    int oD_ = oC_ + __popcll(bC_);                                                \
    int oE_ = oD_ + __popcll(bD_);                                                \
    ull thr_ = ((ull)Ts_ << 32) | (ull)Ti_;                                       \
    (void)thr_;                                                                   \
    if (pA_) { int pos_ = __popcll(bA_ & lt_);       ull key_ = ((ull)sA_<<32)|iA_; WB } \
    if (pB_) { int pos_ = oB_ + __popcll(bB_ & lt_); ull key_ = ((ull)sB_<<32)|iB_; WB } \
    if (pC_) { int pos_ = oC_ + __popcll(bC_ & lt_); ull key_ = ((ull)sC_<<32)|iC_; WB } \
    if (pD_) { int pos_ = oD_ + __popcll(bD_ & lt_); ull key_ = ((ull)sD_<<32)|iD_; WB } \
    if (pE_) { int pos_ = oE_ + __popcll(bE_ & lt_); ull key_ = ((ull)sE_<<32)|iE_; WB } \
    __VA_ARGS__                                                                   \
  }

__global__ __launch_bounds__(1024, 4) void k_fused(const u16* __restrict__ Ah,
                                                   const u16* __restrict__ Al,
                                                   const u16* __restrict__ Bh,
                                                   const u16* __restrict__ Bl,
                                                   const float* __restrict__ aarr,
                                                   const float* __restrict__ sbp,
                                                   ull* __restrict__ lists) {
  __shared__ ull resK[32][FCAP];            // 80 KB reservoir
  __shared__ ull thrK[32];
  __shared__ uint cntK[32];
  __shared__ alignas(16) u16 Bls[2 * JT * D];  // 64 KB: [plane][row][col(swz)]

  const int t = threadIdx.x;
  const int lane = t & 63, wid = t >> 6;
  const int q = lane >> 4, l15 = lane & 15;
  const int ifr = wid >> 3, jfr = wid & 7;
  const int i0 = blockIdx.x * 32;
  const float sb = sbp[0];

  if (t < 32) { cntK[t] = 0u; thrK[t] = 0ULL; }

  // A fragments (hi/lo) -> named registers, 16B loads from linear planes
  int arow = i0 + ifr * 16 + l15; if (arow > N_TOTAL - 1) arow = N_TOTAL - 1;
  const u16* apH = Ah + (size_t)arow * D + q * 8;
  const u16* apL = Al + (size_t)arow * D + q * 8;
  uint4 Ah0 = *(const uint4*)(apH);
  uint4 Ah1 = *(const uint4*)(apH + 32);
  uint4 Ah2 = *(const uint4*)(apH + 64);
  uint4 Ah3 = *(const uint4*)(apH + 96);
  uint4 Al0 = *(const uint4*)(apL);
  uint4 Al1 = *(const uint4*)(apL + 32);
  uint4 Al2 = *(const uint4*)(apL + 64);
  uint4 Al3 = *(const uint4*)(apL + 96);

  int ig0 = i0 + ifr * 16 + q * 4;
  int igc0 = ig0 + 0; if (igc0 > N_TOTAL - 1) igc0 = N_TOTAL - 1;
  int igc1 = ig0 + 1; if (igc1 > N_TOTAL - 1) igc1 = N_TOTAL - 1;
  int igc2 = ig0 + 2; if (igc2 > N_TOTAL - 1) igc2 = N_TOTAL - 1;
  int igc3 = ig0 + 3; if (igc3 > N_TOTAL - 1) igc3 = N_TOTAL - 1;
  const float ai0 = aarr[igc0] + sb;
  const float ai1 = aarr[igc1] + sb;
  const float ai2 = aarr[igc2] + sb;
  const float ai3 = aarr[igc3] + sb;

  const int jl = jfr * 16 + l15;          // 0..127
  const int swz = (jl & 7) << 4;          // byte-XOR for swizzled B reads

  // prefetch tile 0 into named regs
  uint4 stg0, stg1, stg2, stg3;
  PREF(0, stg0, 0) PREF(1, stg1, 0) PREF(2, stg2, 0) PREF(3, stg3, 0)

  for (int tile = 0; tile < NT; ++tile) {
    // compaction check on state after previous tile (skip tile 0).
    // bound: cnt<=FTRIG here => cnt+128 <= FTRIG+128 = FCAP, so no key is ever dropped.
    if (tile > 0) {
      for (int rr = 0; rr < 2; ++rr) {
        int rI = wid + rr * 16;
        uint c = cntK[rI];
        if (c > FTRIG) {
          SEL50(rI, { resK[rI][pos_] = key_; },
                if (lane == 0) { thrK[rI] = thr_; cntK[rI] = TOPK; })
        }
      }
    }
    // stage tile's data (prefetched last iter) into LDS
    STG(0, stg0) STG(1, stg1) STG(2, stg2) STG(3, stg3)
    __syncthreads();  // B1: staged B + compaction thr updates visible

    // prefetch next tile (latency hidden under compute)
    if (tile + 1 < NT) {
      int jb2 = (tile + 1) * JT;
      PREF(0, stg0, jb2) PREF(1, stg1, jb2) PREF(2, stg2, jb2) PREF(3, stg3, jb2)
    }

    const int jb = tile * JT;
    const int jc = jb + jl;
    float ajv = aarr[jc < N_TOTAL ? jc : N_TOTAL - 1];

    // MFMA: same operand order as proven k_score (AhBh, AhBl, AlBh per k-step)
    f32x4 acc = (f32x4){0.f, 0.f, 0.f, 0.f};
    const char* bbase = (const char*)Bls + (size_t)jl * 256;
    MM(0, Ah0, Al0) MM(1, Ah1, Al1) MM(2, Ah2, Al2) MM(3, Ah3, Al3)

    // filter into reservoir
    if (jc < N_TOTAL) {
      FILT(0, ai0) FILT(1, ai1) FILT(2, ai2) FILT(3, ai3)
    }
    __syncthreads();  // B2: inserts visible to next compaction check
  }

  // final exact top-50 per row -> lists (unsorted; k_write is order-invariant)
  for (int rr = 0; rr < 2; ++rr) {
    int rI = wid + rr * 16;
    int ig = i0 + rI;
    uint c = cntK[rI];
    if (ig < N_TOTAL) {
      SEL50(rI, { lists[(size_t)ig * TOPK + pos_] = key_; }, )
    }
  }
}

// ---------------- K4: softmax + sparse write of S (single HBM pass over S) ----------------
__global__ __launch_bounds__(256) void k_write(const ull* __restrict__ lists,
                                               float* __restrict__ S) {
  const int t = threadIdx.x;
  const int lane = t & 63, wid = t >> 6;
  const int row = blockIdx.x * 4 + wid;

  ull key = (lane < TOPK) ? lists[(size_t)row * TOPK + lane] : 0ULL;
  float xv = (lane < TOPK) ? __uint_as_float((uint)(key >> 32)) : -1e30f;
  float mx = xv;
#pragma unroll
  for (int off = 32; off >= 1; off >>= 1) mx = fmaxf(mx, __shfl_xor(mx, off));
  float e = (lane < TOPK) ? expf(xv - mx) : 0.f;
  float ss = e;
#pragma unroll
  for (int off = 32; off >= 1; off >>= 1) ss += __shfl_xor(ss, off);
  float sv = e / ss;
  uint j = 0xFFFFFFFFu - (uint)(key & 0xFFFFFFFFu);

  float4* wp = (float4*)(S + (size_t)row * N_TOTAL);
  float4 z = make_float4(0.f, 0.f, 0.f, 0.f);
  for (int c = lane; c < N_TOTAL / 4; c += 64) wp[c] = z;
  __syncthreads();  // drain zero-stores before scatter (same-address ordering)
  if (lane < TOPK) S[(size_t)row * N_TOTAL + j] = sv;
}

extern "C" void kernel_launch(void* const* d_in, const int* in_sizes, int n_in,
                              void* d_out, int out_size, void* d_ws, size_t ws_size,
                              hipStream_t stream) {
  const float* in    = (const float*)d_in[0];
  const float* W1    = (const float*)d_in[1];
  const float* b1    = (const float*)d_in[2];
  const float* gamma = (const float*)d_in[3];
  const float* beta  = (const float*)d_in[4];
  const float* sw    = (const float*)d_in[5];
  const float* sb    = (const float*)d_in[6];
  float* out_f = (float*)d_out;
  float* S = out_f + (size_t)N_TOTAL * D;  // [10000,10000]

  // ws layout (~24.6 MB)
  float* wsf  = (float*)d_ws;
  float* x    = wsf;                               // 1,280,000 f
  float* outf = wsf + 1280000;                     // 1,280,000 f
  float* aarr = wsf + 2560000;                     // 10,000 f
  u16* Ah = (u16*)(wsf + 2570000);                 // 1,280,000 u16 each
  u16* Al = Ah + 1280000;
  u16* Bh = Al + 1280000;
  u16* Bl = Bh + 1280000;
  ull* lists = (ull*)(Bl + 1280000);               // 10000*50 u64 = 4 MB

  hipMemsetAsync(x, 0, (size_t)N_TOTAL * D * sizeof(float), stream);
  k_gemm1<<<dim3(79, 4), 256, 0, stream>>>(in, W1, x);
  k_bn<<<100, 128, 0, stream>>>(x, b1, gamma, beta, sw, out_f, outf, Ah, Al, Bh, Bl);
  k_arow<<<2500, 256, 0, stream>>>(outf, sw, aarr);
  k_fused<<<313, 1024, 0, stream>>>(Ah, Al, Bh, Bl, aarr, sb, lists);
  k_write<<<2500, 256, 0, stream>>>(lists, S);
}